// Round 7
// baseline (45.206 us; speedup 1.0000x reference)
//
#include <hip/hip_runtime.h>
#include <stdint.h>

// CenterNet postprocess: y_pred (32, 84, 128, 128) f32 -> (32, 100, 8) f32
//
// Round-7: balance pass1 to exact machine capacity.
//   k_pass1 : 2048 blocks (= 256 CU x 8 co-resident 256-thr blocks), each
//             grid-strides 5 of 10240 fine tiles (4096 floats). Register
//             double-buffer of the next tile's 4 float4 loads. Stream-screen
//             v >= 3.6 via per-float4 max-guard; rare hits (~0.65/tile) are
//             3x3-NMS-tested and stored to the tile's PRIVATE 16-slot region
//             of cand; per-tile count stored unconditionally (no memset, no
//             global atomics).
//   k_finalize (256 thr, 1 block/batch): 3-level prefix over 320 tile counts,
//             gather, bitonic-sort (value,~index) keys, emit top-100 in exact
//             lax.top_k order. Any tile overflow or total outside [100,4096]
//             -> exact in-block histogram fallback (never taken on bench).

#define NCLS   80
#define NCH    84
#define WD     128
#define HD     128
#define HWD    16384
#define NPB    (NCLS * HWD)     // 1310720 heatmap elements per batch
#define NBINS  4096
#define SKCAP  4096
#define MAXDET 100
#define NBATCH 32
#define STHR   3.6f             // static screen threshold (true p100 ~ 3.79)
#define TILE   4096             // floats per tile
#define TPB_T  320              // tiles per batch  (NPB / TILE)
#define NTILE  10240            // total tiles      (TPB_T * NBATCH)
#define NGRID  2048             // pass1 blocks     (exact co-residency)
#define SLOT   16               // candidate slots per tile

// ws layout (bytes):
#define CNT_OFF  0              // 10240*4 = 40960 (pad to 65536)
#define CAND_OFF 65536          // 10240*16*8 = 1310720
// total 1376256

__device__ __forceinline__ uint32_t fsort(float f) {
  uint32_t u = __float_as_uint(f);
  return u ^ ((u & 0x80000000u) ? 0xFFFFFFFFu : 0x80000000u);
}
__device__ __forceinline__ float funsort(uint32_t u) {
  uint32_t b = (u & 0x80000000u) ? (u ^ 0x80000000u) : ~u;
  return __uint_as_float(b);
}

// exact 3x3 NMS max-of-neighbors for heatmap element e (within one batch)
__device__ __forceinline__ float nms_nbmax(const float* __restrict__ hmb, int e,
                                           float v) {
  int sp = e & (HWD - 1);
  int h = sp >> 7, w = sp & (WD - 1);
  const float* p = hmb + e;
  float m = v;
  bool wl = (w > 0), wr = (w < WD - 1);
  if (wl) m = fmaxf(m, p[-1]);
  if (wr) m = fmaxf(m, p[1]);
  if (h > 0) {
    m = fmaxf(m, p[-WD]);
    if (wl) m = fmaxf(m, p[-WD - 1]);
    if (wr) m = fmaxf(m, p[-WD + 1]);
  }
  if (h < HD - 1) {
    m = fmaxf(m, p[WD]);
    if (wl) m = fmaxf(m, p[WD - 1]);
    if (wr) m = fmaxf(m, p[WD + 1]);
  }
  return m;
}

__device__ __forceinline__ uint64_t make_key(uint32_t u, int e) {
  int sp = e & (HWD - 1);
  uint32_t fi = (uint32_t)(sp * NCLS + (e >> 14));  // (H,W,C) flat index
  return ((uint64_t)u << 32) | (uint32_t)(~fi);
}

// ---------------- pass 1: balanced streaming screen -------------------------
extern "C" __global__ __launch_bounds__(256)
void k_pass1(const float* __restrict__ in, uint64_t* __restrict__ cand,
             uint32_t* __restrict__ cnt) {
  __shared__ uint32_t lcnt;
  const int t = threadIdx.x;

  // tile k (k=0..4): tile id = blockIdx.x + k*NGRID
  int tk0 = blockIdx.x;
  int b0 = tk0 / TPB_T;
  const float* hm0 = in + (size_t)b0 * NCH * HWD;
  int e00 = (tk0 % TPB_T) * TILE + t * 4;

  float4 cur0 = *reinterpret_cast<const float4*>(hm0 + e00);
  float4 cur1 = *reinterpret_cast<const float4*>(hm0 + e00 + 1024);
  float4 cur2 = *reinterpret_cast<const float4*>(hm0 + e00 + 2048);
  float4 cur3 = *reinterpret_cast<const float4*>(hm0 + e00 + 3072);

#pragma unroll
  for (int k = 0; k < 5; ++k) {
    const int tk = blockIdx.x + k * NGRID;
    const int b = tk / TPB_T;
    const float* hmb = in + (size_t)b * NCH * HWD;
    const int e0 = (tk % TPB_T) * TILE + t * 4;

    // prefetch next tile while processing this one
    float4 nxt0, nxt1, nxt2, nxt3;
    if (k < 4) {
      const int tkn = blockIdx.x + (k + 1) * NGRID;
      const int bn = tkn / TPB_T;
      const float* hmn = in + (size_t)bn * NCH * HWD;
      const int en = (tkn % TPB_T) * TILE + t * 4;
      nxt0 = *reinterpret_cast<const float4*>(hmn + en);
      nxt1 = *reinterpret_cast<const float4*>(hmn + en + 1024);
      nxt2 = *reinterpret_cast<const float4*>(hmn + en + 2048);
      nxt3 = *reinterpret_cast<const float4*>(hmn + en + 3072);
    }

    if (t == 0) lcnt = 0;
    __syncthreads();

    uint64_t* cb = cand + (size_t)tk * SLOT;
#define SCREEN(w4, roff)                                                    \
    {                                                                       \
      float m4_ = fmaxf(fmaxf(w4.x, w4.y), fmaxf(w4.z, w4.w));              \
      if (m4_ >= STHR) {                                                    \
        int r_ = e0 + roff;                                                 \
        if (w4.x >= STHR && w4.x == nms_nbmax(hmb, r_ + 0, w4.x)) {         \
          uint32_t p_ = atomicAdd(&lcnt, 1u);                               \
          if (p_ < SLOT) cb[p_] = make_key(fsort(w4.x), r_ + 0); }          \
        if (w4.y >= STHR && w4.y == nms_nbmax(hmb, r_ + 1, w4.y)) {         \
          uint32_t p_ = atomicAdd(&lcnt, 1u);                               \
          if (p_ < SLOT) cb[p_] = make_key(fsort(w4.y), r_ + 1); }          \
        if (w4.z >= STHR && w4.z == nms_nbmax(hmb, r_ + 2, w4.z)) {         \
          uint32_t p_ = atomicAdd(&lcnt, 1u);                               \
          if (p_ < SLOT) cb[p_] = make_key(fsort(w4.z), r_ + 2); }          \
        if (w4.w >= STHR && w4.w == nms_nbmax(hmb, r_ + 3, w4.w)) {         \
          uint32_t p_ = atomicAdd(&lcnt, 1u);                               \
          if (p_ < SLOT) cb[p_] = make_key(fsort(w4.w), r_ + 3); }          \
      }                                                                     \
    }
    SCREEN(cur0, 0) SCREEN(cur1, 1024) SCREEN(cur2, 2048) SCREEN(cur3, 3072)
#undef SCREEN

    __syncthreads();
    if (t == 0) cnt[tk] = lcnt;  // raw count; >SLOT triggers exact fallback

    cur0 = nxt0; cur1 = nxt1; cur2 = nxt2; cur3 = nxt3;
  }
}

// ---------------- finalize: gather (+exact fallback) + sort + emit ----------
extern "C" __global__ __launch_bounds__(256)
void k_finalize(const float* __restrict__ in, const uint64_t* __restrict__ cand,
                const uint32_t* __restrict__ cnt, float* __restrict__ out) {
  const int b = blockIdx.x;
  const int t = threadIdx.x;
  const float* hmb = in + (size_t)b * NCH * HWD;

  __shared__ uint64_t sk[SKCAP];       // 32 KB
  __shared__ uint32_t hist[NBINS];     // 16 KB (fallback only)
  __shared__ uint32_t tc[TPB_T];       // tile counts
  __shared__ uint32_t tp[TPB_T + 1];   // tile prefix sums
  __shared__ uint32_t g64[65];
  __shared__ uint32_t scnB[256];       // fallback bin scan
  __shared__ uint32_t flags, sthr_s, lcnt;

  if (t == 0) { flags = 0; sthr_s = 0; lcnt = 0; }
  __syncthreads();

  for (int i = t; i < TPB_T; i += 256) {
    uint32_t c = cnt[(size_t)b * TPB_T + i];
    tc[i] = c;
    if (c > SLOT) atomicOr(&flags, 1u);
  }
  __syncthreads();
  // 3-level prefix scan: 64 groups of 5
  if (t < 64) {
    uint32_t s = 0;
#pragma unroll
    for (int j = 0; j < 5; ++j) s += tc[t * 5 + j];
    g64[t] = s;
  }
  __syncthreads();
  if (t == 0) {
    uint32_t acc = 0;
    for (int i = 0; i < 64; ++i) { uint32_t u = g64[i]; g64[i] = acc; acc += u; }
    g64[64] = acc;
  }
  __syncthreads();
  if (t < 64) {
    uint32_t acc = g64[t];
#pragma unroll
    for (int j = 0; j < 5; ++j) { tp[t * 5 + j] = acc; acc += tc[t * 5 + j]; }
  }
  if (t == 0) tp[TPB_T] = g64[64];
  __syncthreads();

  uint32_t n = tp[TPB_T];
  bool fb = (flags != 0) || (n < MAXDET) || (n > SKCAP);

  if (!fb) {
    // gather per-tile segments into contiguous sk[0..n)
    const uint64_t* cb = cand + (size_t)b * TPB_T * SLOT;
    for (int i = t; i < TPB_T; i += 256) {
      uint32_t off = tp[i], ci = tc[i];
      for (uint32_t j = 0; j < ci; ++j) sk[off + j] = cb[(size_t)i * SLOT + j];
    }
  } else {
    // ---- exact in-block fallback (arbitrary inputs; never taken on bench) --
    for (int i = t; i < NBINS; i += 256) hist[i] = 0;
    __syncthreads();
    uint32_t zp = 0, zn = 0;
    for (int e = t; e < NPB; e += 256) {
      float v = hmb[e];
      if (v == nms_nbmax(hmb, e, v)) {
        atomicAdd(&hist[fsort(v) >> 20], 1u);
      } else if (__float_as_uint(v) >> 31) zn++; else zp++;
    }
    for (int off = 32; off; off >>= 1) {
      zp += __shfl_down(zp, off);
      zn += __shfl_down(zn, off);
    }
    if ((t & 63) == 0) {
      if (zp) atomicAdd(&hist[2048], zp);  // suppressed +0.0
      if (zn) atomicAdd(&hist[2047], zn);  // suppressed -0.0
    }
    __syncthreads();
    uint32_t loc[16], own = 0;
#pragma unroll
    for (int i = 0; i < 16; ++i) { loc[i] = hist[t * 16 + i]; own += loc[i]; }
    scnB[t] = own;
    __syncthreads();
    if (t == 0) {
      uint32_t acc = 0;
      for (int j = 255; j >= 0; --j) { uint32_t v = scnB[j]; scnB[j] = acc; acc += v; }
    }
    __syncthreads();
    uint32_t above = scnB[t];
    if (above < MAXDET && above + own >= MAXDET) {
      uint32_t cum = above;
      for (int i = 15; i >= 0; --i) {
        cum += loc[i];
        if (cum >= MAXDET) { sthr_s = (uint32_t)(t * 16 + i); break; }
      }
    }
    __syncthreads();
    uint32_t uthr = sthr_s << 20;
    for (int e = t; e < NPB; e += 256) {
      float v = hmb[e];
      bool kept = (v == nms_nbmax(hmb, e, v));
      float nv = kept ? v : 0.0f * v;
      uint32_t u = fsort(nv);
      if (u >= uthr) {
        uint32_t pos = atomicAdd(&lcnt, 1u);
        if (pos < SKCAP) sk[pos] = make_key(u, e);
      }
    }
    __syncthreads();
    n = lcnt; if (n > SKCAP) n = SKCAP;
  }
  __syncthreads();

  uint32_t m = 128; while (m < n) m <<= 1;
  for (uint32_t i = t; i < m; i += 256) if (i >= n) sk[i] = 0ull;
  __syncthreads();

  // bitonic sort descending by (value, ~fi): value desc, index asc on ties
  for (uint32_t k = 2; k <= m; k <<= 1) {
    for (uint32_t j = k >> 1; j > 0; j >>= 1) {
      for (uint32_t i = t; i < m; i += 256) {
        uint32_t ixj = i ^ j;
        if (ixj > i && ixj < m) {
          uint64_t a = sk[i], c = sk[ixj];
          bool desc = (i & k) == 0;
          if (desc ? (a < c) : (a > c)) { sk[i] = c; sk[ixj] = a; }
        }
      }
      __syncthreads();
    }
  }

  if (t < MAXDET) {
    uint64_t key = sk[t];
    uint32_t u = (uint32_t)(key >> 32);
    uint32_t fi = ~((uint32_t)key);
    float score = funsort(u);
    uint32_t c = fi % NCLS;
    uint32_t sp = (fi / NCLS) & (HWD - 1);
    float xs = (float)(sp & (WD - 1));
    float ys = (float)(sp >> 7);
    const float* gp = in + ((size_t)b * NCH + NCLS) * HWD + sp;
    float g0 = gp[0], g1 = gp[HWD], g2 = gp[2 * HWD], g3 = gp[3 * HWD];
    float* o = out + ((size_t)b * MAXDET + t) * 8;
    o[0] = (float)(c + 1);
    o[1] = score;
    o[2] = (4.0f * xs - g0) * (1.0f / 512.0f);
    o[3] = (4.0f * ys - g1) * (1.0f / 512.0f);
    o[4] = (4.0f * xs + g2) * (1.0f / 512.0f);
    o[5] = (4.0f * ys + g3) * (1.0f / 512.0f);
    o[6] = ys;
    o[7] = xs;
  }
}

extern "C" void kernel_launch(void* const* d_in, const int* in_sizes, int n_in,
                              void* d_out, int out_size, void* d_ws, size_t ws_size,
                              hipStream_t stream) {
  (void)in_sizes; (void)n_in; (void)out_size; (void)ws_size;
  const float* in = (const float*)d_in[0];
  float* out = (float*)d_out;
  uint8_t* ws = (uint8_t*)d_ws;

  uint32_t* cnt  = (uint32_t*)(ws + CNT_OFF);
  uint64_t* cand = (uint64_t*)(ws + CAND_OFF);

  k_pass1<<<NGRID, 256, 0, stream>>>(in, cand, cnt);
  k_finalize<<<NBATCH, 256, 0, stream>>>(in, cand, cnt, out);
}

// Round 8
// 44.852 us; speedup vs baseline: 1.0079x; 1.0079x over previous
//
#include <hip/hip_runtime.h>
#include <stdint.h>

// CenterNet postprocess: y_pred (32, 84, 128, 128) f32 -> (32, 100, 8) f32
//
// Round-8: revert to round-6 pass1 shape (round-7 rebalance was null) and add
// nontemporal streaming loads (single-use data; avoid L2 thrash on ingest).
//   k_pass1 : grid (160,32) x 256 thr; each block screens 8192 contiguous
//             floats via 8 nontemporal float4 loads/thread; v >= 3.6 max4
//             guard; rare hits (~208/batch) 3x3-NMS-tested via normal cached
//             re-reads; private 32-slot cand region per block; count stored
//             unconditionally (no memset, no global atomics).
//   k_finalize (256 thr, 1 block/batch): prefix-sum 160 block counts, gather,
//             bitonic-sort (value,~index) keys, emit top-100 in exact
//             lax.top_k order. Any block overflow or total outside [100,4096]
//             -> exact in-block histogram fallback (never taken on bench).

#define NCLS   80
#define NCH    84
#define WD     128
#define HD     128
#define HWD    16384
#define NPB    (NCLS * HWD)     // 1310720 heatmap elements per batch
#define NBINS  4096
#define SKCAP  4096
#define MAXDET 100
#define NBATCH 32
#define STHR   3.6f             // static screen threshold (true p100 ~ 3.79)
#define NBLK   160              // pass1 blocks per batch
#define SLOT   32               // candidate slots per pass1 block

// ws layout (bytes):
#define CNT_OFF  0              // 32*160*4 = 20480 (pad to 32768)
#define CAND_OFF 32768          // 32*160*32*8 = 1310720

typedef float f4 __attribute__((ext_vector_type(4)));

__device__ __forceinline__ uint32_t fsort(float f) {
  uint32_t u = __float_as_uint(f);
  return u ^ ((u & 0x80000000u) ? 0xFFFFFFFFu : 0x80000000u);
}
__device__ __forceinline__ float funsort(uint32_t u) {
  uint32_t b = (u & 0x80000000u) ? (u ^ 0x80000000u) : ~u;
  return __uint_as_float(b);
}

// exact 3x3 NMS max-of-neighbors for heatmap element e (within one batch)
__device__ __forceinline__ float nms_nbmax(const float* __restrict__ hmb, int e,
                                           float v) {
  int sp = e & (HWD - 1);
  int h = sp >> 7, w = sp & (WD - 1);
  const float* p = hmb + e;
  float m = v;
  bool wl = (w > 0), wr = (w < WD - 1);
  if (wl) m = fmaxf(m, p[-1]);
  if (wr) m = fmaxf(m, p[1]);
  if (h > 0) {
    m = fmaxf(m, p[-WD]);
    if (wl) m = fmaxf(m, p[-WD - 1]);
    if (wr) m = fmaxf(m, p[-WD + 1]);
  }
  if (h < HD - 1) {
    m = fmaxf(m, p[WD]);
    if (wl) m = fmaxf(m, p[WD - 1]);
    if (wr) m = fmaxf(m, p[WD + 1]);
  }
  return m;
}

__device__ __forceinline__ uint64_t make_key(uint32_t u, int e) {
  int sp = e & (HWD - 1);
  uint32_t fi = (uint32_t)(sp * NCLS + (e >> 14));  // (H,W,C) flat index
  return ((uint64_t)u << 32) | (uint32_t)(~fi);
}

// ---------------- pass 1: nontemporal streaming screen ----------------------
// grid (160, 32) x 256 threads; each block screens 8192 contiguous floats.
extern "C" __global__ __launch_bounds__(256)
void k_pass1(const float* __restrict__ in, uint64_t* __restrict__ cand,
             uint32_t* __restrict__ cnt) {
  __shared__ uint32_t lcnt;
  __shared__ uint64_t lbuf[SLOT];
  if (threadIdx.x == 0) lcnt = 0;
  __syncthreads();

  const int b = blockIdx.y;
  const int blk = blockIdx.x;
  const float* hmb = in + (size_t)b * NCH * HWD;
  const int base = blk * 8192 + (int)threadIdx.x * 4;

  f4 v[8];
#pragma unroll
  for (int it = 0; it < 8; ++it)
    v[it] = __builtin_nontemporal_load(
        reinterpret_cast<const f4*>(hmb + base + it * 1024));

#pragma unroll
  for (int it = 0; it < 8; ++it) {
    f4 w = v[it];
    float m4 = fmaxf(fmaxf(w.x, w.y), fmaxf(w.z, w.w));
    if (m4 >= STHR) {  // rare: one branch guards the detailed checks
      int r = base + it * 1024;
#define TRY(vi, off)                                                     \
      if (vi >= STHR && vi == nms_nbmax(hmb, r + off, vi)) {             \
        uint32_t pos = atomicAdd(&lcnt, 1u);                             \
        if (pos < SLOT) lbuf[pos] = make_key(fsort(vi), r + off);        \
      }
      TRY(w.x, 0) TRY(w.y, 1) TRY(w.z, 2) TRY(w.w, 3)
#undef TRY
    }
  }
  __syncthreads();

  uint32_t n = lcnt;
  uint64_t* cb = cand + ((size_t)b * NBLK + blk) * SLOT;
  uint32_t nn = (n < SLOT) ? n : SLOT;
  for (uint32_t i = threadIdx.x; i < nn; i += 256) cb[i] = lbuf[i];
  // raw count (may exceed SLOT -> finalize takes exact fallback)
  if (threadIdx.x == 0) cnt[(size_t)b * NBLK + blk] = n;
}

// ---------------- finalize: gather (+exact fallback) + sort + emit ----------
extern "C" __global__ __launch_bounds__(256)
void k_finalize(const float* __restrict__ in, const uint64_t* __restrict__ cand,
                const uint32_t* __restrict__ cnt, float* __restrict__ out) {
  const int b = blockIdx.x;
  const int t = threadIdx.x;
  const float* hmb = in + (size_t)b * NCH * HWD;

  __shared__ uint64_t sk[SKCAP];       // 32 KB
  __shared__ uint32_t hist[NBINS];     // 16 KB (fallback only)
  __shared__ uint32_t pfx[NBLK + 1];   // block-count prefix sums
  __shared__ uint32_t scnB[256];       // fallback bin scan
  __shared__ uint32_t flags, sthr_s, lcnt;

  if (t == 0) { flags = 0; sthr_s = 0; lcnt = 0; }
  __syncthreads();

  if (t < NBLK) {
    uint32_t c = cnt[(size_t)b * NBLK + t];
    if (c > SLOT) atomicOr(&flags, 1u);
    pfx[t] = c;
  }
  __syncthreads();
  if (t == 0) {
    uint32_t acc = 0;
    for (int i = 0; i < NBLK; ++i) { uint32_t u = pfx[i]; pfx[i] = acc; acc += u; }
    pfx[NBLK] = acc;
  }
  __syncthreads();

  uint32_t n = pfx[NBLK];
  bool fb = (flags != 0) || (n < MAXDET) || (n > SKCAP);

  if (!fb) {
    // gather per-block segments into contiguous sk[0..n)
    const uint64_t* cb = cand + (size_t)b * NBLK * SLOT;
    for (int i = t; i < NBLK; i += 256) {
      uint32_t off = pfx[i], ci = pfx[i + 1] - off;
      for (uint32_t j = 0; j < ci; ++j) sk[off + j] = cb[(size_t)i * SLOT + j];
    }
  } else {
    // ---- exact in-block fallback (arbitrary inputs; never taken on bench) --
    for (int i = t; i < NBINS; i += 256) hist[i] = 0;
    __syncthreads();
    uint32_t zp = 0, zn = 0;
    for (int e = t; e < NPB; e += 256) {
      float v = hmb[e];
      if (v == nms_nbmax(hmb, e, v)) {
        atomicAdd(&hist[fsort(v) >> 20], 1u);
      } else if (__float_as_uint(v) >> 31) zn++; else zp++;
    }
    for (int off = 32; off; off >>= 1) {
      zp += __shfl_down(zp, off);
      zn += __shfl_down(zn, off);
    }
    if ((t & 63) == 0) {
      if (zp) atomicAdd(&hist[2048], zp);  // suppressed +0.0
      if (zn) atomicAdd(&hist[2047], zn);  // suppressed -0.0
    }
    __syncthreads();
    uint32_t loc[16], own = 0;
#pragma unroll
    for (int i = 0; i < 16; ++i) { loc[i] = hist[t * 16 + i]; own += loc[i]; }
    scnB[t] = own;
    __syncthreads();
    if (t == 0) {
      uint32_t acc = 0;
      for (int j = 255; j >= 0; --j) { uint32_t v = scnB[j]; scnB[j] = acc; acc += v; }
    }
    __syncthreads();
    uint32_t above = scnB[t];
    if (above < MAXDET && above + own >= MAXDET) {
      uint32_t cum = above;
      for (int i = 15; i >= 0; --i) {
        cum += loc[i];
        if (cum >= MAXDET) { sthr_s = (uint32_t)(t * 16 + i); break; }
      }
    }
    __syncthreads();
    uint32_t uthr = sthr_s << 20;
    for (int e = t; e < NPB; e += 256) {
      float v = hmb[e];
      bool kept = (v == nms_nbmax(hmb, e, v));
      float nv = kept ? v : 0.0f * v;
      uint32_t u = fsort(nv);
      if (u >= uthr) {
        uint32_t pos = atomicAdd(&lcnt, 1u);
        if (pos < SKCAP) sk[pos] = make_key(u, e);
      }
    }
    __syncthreads();
    n = lcnt; if (n > SKCAP) n = SKCAP;
  }
  __syncthreads();

  uint32_t m = 128; while (m < n) m <<= 1;
  for (uint32_t i = t; i < m; i += 256) if (i >= n) sk[i] = 0ull;
  __syncthreads();

  // bitonic sort descending by (value, ~fi): value desc, index asc on ties
  for (uint32_t k = 2; k <= m; k <<= 1) {
    for (uint32_t j = k >> 1; j > 0; j >>= 1) {
      for (uint32_t i = t; i < m; i += 256) {
        uint32_t ixj = i ^ j;
        if (ixj > i && ixj < m) {
          uint64_t a = sk[i], c = sk[ixj];
          bool desc = (i & k) == 0;
          if (desc ? (a < c) : (a > c)) { sk[i] = c; sk[ixj] = a; }
        }
      }
      __syncthreads();
    }
  }

  if (t < MAXDET) {
    uint64_t key = sk[t];
    uint32_t u = (uint32_t)(key >> 32);
    uint32_t fi = ~((uint32_t)key);
    float score = funsort(u);
    uint32_t c = fi % NCLS;
    uint32_t sp = (fi / NCLS) & (HWD - 1);
    float xs = (float)(sp & (WD - 1));
    float ys = (float)(sp >> 7);
    const float* gp = in + ((size_t)b * NCH + NCLS) * HWD + sp;
    float g0 = gp[0], g1 = gp[HWD], g2 = gp[2 * HWD], g3 = gp[3 * HWD];
    float* o = out + ((size_t)b * MAXDET + t) * 8;
    o[0] = (float)(c + 1);
    o[1] = score;
    o[2] = (4.0f * xs - g0) * (1.0f / 512.0f);
    o[3] = (4.0f * ys - g1) * (1.0f / 512.0f);
    o[4] = (4.0f * xs + g2) * (1.0f / 512.0f);
    o[5] = (4.0f * ys + g3) * (1.0f / 512.0f);
    o[6] = ys;
    o[7] = xs;
  }
}

extern "C" void kernel_launch(void* const* d_in, const int* in_sizes, int n_in,
                              void* d_out, int out_size, void* d_ws, size_t ws_size,
                              hipStream_t stream) {
  (void)in_sizes; (void)n_in; (void)out_size; (void)ws_size;
  const float* in = (const float*)d_in[0];
  float* out = (float*)d_out;
  uint8_t* ws = (uint8_t*)d_ws;

  uint32_t* cnt  = (uint32_t*)(ws + CNT_OFF);
  uint64_t* cand = (uint64_t*)(ws + CAND_OFF);

  k_pass1<<<dim3(NBLK, NBATCH), 256, 0, stream>>>(in, cand, cnt);
  k_finalize<<<NBATCH, 256, 0, stream>>>(in, cand, cnt, out);
}